// Round 5
// baseline (11015.649 us; speedup 1.0000x reference)
//
#include <hip/hip_runtime.h>
#include <hip/hip_bf16.h>

#define VV 30000
#define HH 512
#define NC 9
#define BB 128
#define TT 256
#define GG 2048
#define TB (TT*BB)

using short8 = __attribute__((ext_vector_type(8))) short;
using f32x4  = __attribute__((ext_vector_type(4))) float;

__device__ inline float bf2f(unsigned short u){
    union { unsigned int i; float f; } v; v.i = ((unsigned int)u) << 16; return v.f;
}
__device__ inline unsigned short f2bf(float f){
    union { unsigned int i; float f; } v; v.f = f;
    unsigned int x = v.i;
    unsigned int r = (x + 0x7fffu + ((x >> 16) & 1u)) >> 16;
    return (unsigned short)r;
}
__device__ inline float sigm(float x){
    if (x >= 0.f){ return 1.f / (1.f + __expf(-x)); }
    float e = __expf(x); return e / (1.f + e);
}
__device__ inline float tanh_f(float x){
    float ax = fabsf(x);
    float e = __expf(-2.f * ax);
    float t = (1.f - e) / (1.f + e);
    return copysignf(t, x);
}

// ---------------- weight cast fp32 -> bf16 ----------------
__global__ void castbf(const float* __restrict__ in, unsigned short* __restrict__ out, int n){
    int i = blockIdx.x * blockDim.x + threadIdx.x;
    if (i < n) out[i] = f2bf(in[i]);
}

// ---------------- embedding + renorm -> xs bf16 [T*B][H] ----------------
__global__ __launch_bounds__(256) void embed_k(const int* __restrict__ x,
                                               const float* __restrict__ embed,
                                               unsigned short* __restrict__ xs){
    int wid  = (int)((blockIdx.x * blockDim.x + threadIdx.x) >> 6);
    int lane = threadIdx.x & 63;
    if (wid >= TB) return;
    int t = wid >> 7, b = wid & 127;
    int tok = x[b * TT + t];
    const float4* e = (const float4*)(embed + (size_t)tok * HH);
    float4 v0 = e[lane], v1 = e[lane + 64];
    float ss = v0.x*v0.x + v0.y*v0.y + v0.z*v0.z + v0.w*v0.w
             + v1.x*v1.x + v1.y*v1.y + v1.z*v1.z + v1.w*v1.w;
    #pragma unroll
    for (int off = 32; off > 0; off >>= 1) ss += __shfl_xor(ss, off, 64);
    float nrm = sqrtf(ss);
    float sc = (nrm > 1.f) ? 1.f / (nrm + 1e-7f) : 1.f;
    unsigned short* dst = xs + (size_t)wid * HH;
    ushort4 o0, o1;
    o0.x = f2bf(v0.x * sc); o0.y = f2bf(v0.y * sc); o0.z = f2bf(v0.z * sc); o0.w = f2bf(v0.w * sc);
    o1.x = f2bf(v1.x * sc); o1.y = f2bf(v1.y * sc); o1.z = f2bf(v1.z * sc); o1.w = f2bf(v1.w * sc);
    ((ushort4*)dst)[lane]      = o0;
    ((ushort4*)dst)[lane + 64] = o1;
}

// ---------------- bf16 GEMM (both dirs via blockIdx.z): C = A@W^T + bias ----------------
// grid: (M/128, GG/128, 2); block 256 (4 waves, 2x2 of 64x64 wave tiles)
__global__ __launch_bounds__(256) void gemm2(const unsigned short* __restrict__ A0,
                                             const unsigned short* __restrict__ A1,
                                             const unsigned short* __restrict__ Wb_,
                                             const float* __restrict__ bias,
                                             unsigned short* __restrict__ Cout,
                                             int K, int CH){
    const int dz = blockIdx.z;
    const unsigned short* A  = dz ? A1 : A0;
    const unsigned short* W  = Wb_ + (size_t)dz * GG * K;
    const float*          bd = bias + dz * GG;
    unsigned short*       C  = Cout + (size_t)dz * CH * BB * GG;

    int lane = threadIdx.x & 63;
    int wv   = threadIdx.x >> 6;
    int m0   = blockIdx.x * 128 + (wv >> 1) * 64;
    int n0   = blockIdx.y * 128 + (wv & 1) * 64;
    int l15  = lane & 15, quad = lane >> 4;

    f32x4 acc[4][4];
    #pragma unroll
    for (int i = 0; i < 4; i++)
        #pragma unroll
        for (int j = 0; j < 4; j++){ acc[i][j][0]=0.f; acc[i][j][1]=0.f; acc[i][j][2]=0.f; acc[i][j][3]=0.f; }

    const unsigned short* Ab = A + (size_t)(m0 + l15) * K + quad * 8;
    const unsigned short* Wp = W + (size_t)(n0 + l15) * K + quad * 8;

    for (int kk = 0; kk < K; kk += 32){
        short8 a[4], bfr[4];
        #pragma unroll
        for (int i = 0; i < 4; i++) a[i]   = *(const short8*)(Ab + (size_t)i * 16 * K + kk);
        #pragma unroll
        for (int j = 0; j < 4; j++) bfr[j] = *(const short8*)(Wp + (size_t)j * 16 * K + kk);
        #pragma unroll
        for (int i = 0; i < 4; i++)
            #pragma unroll
            for (int j = 0; j < 4; j++)
                acc[i][j] = __builtin_amdgcn_mfma_f32_16x16x32_bf16(a[i], bfr[j], acc[i][j], 0, 0, 0);
    }

    #pragma unroll
    for (int i = 0; i < 4; i++){
        #pragma unroll
        for (int j = 0; j < 4; j++){
            int n = n0 + j * 16 + l15;
            float bn = bd[n];
            #pragma unroll
            for (int r = 0; r < 4; r++){
                int m = m0 + i * 16 + quad * 4 + r;
                C[(size_t)m * GG + n] = f2bf(acc[i][j][r] + bn);
            }
        }
    }
}

// ---------------- persistent BiLSTM recurrence ----------------
// grid: 128 blocks = d(2) x jc(32) x mh(2); block 256 = 4 waves (one gate each).
// W_hh slice lives in LDS (immune to agent-fence L2 invalidation and compiler
// rematerialization — round-4's 200MB/dispatch weight re-fetch bug).
// Barrier is per-(d,mh) group: 4 counters x 32 arrivals (the only data dep).
// Layer-1 mode (cw != nullptr): emissions fused via atomicAdd, no hs buffer.
__global__ __launch_bounds__(256) void lstm_seq(const unsigned short* __restrict__ preC, // [2][CH][128][2048]
                                                const unsigned short* __restrict__ whh,  // [2][2048][512]
                                                unsigned short* __restrict__ hA,         // [2][128][512]
                                                unsigned short* __restrict__ hB,
                                                float* __restrict__ cstate,              // [2][128][512]
                                                unsigned short* __restrict__ hs_out,     // [TB][1024] (layer0)
                                                const float* __restrict__ cw,            // [9][1024] (layer1) or null
                                                float* __restrict__ em,                  // [T*B][9]  (layer1)
                                                int t0, int nsteps, int CH,
                                                unsigned int* __restrict__ bar){
    __shared__ unsigned short w_s[4][16][520];  // 66.6 KB, +8 pad -> 2-way conflicts only (free)
    __shared__ float z[4 * 64 * 17];            // 17.4 KB
    __shared__ float hrow[64 * 17];             // 4.3 KB (layer-1 emission staging)
    __shared__ float cw_s[NC][16];

    const int tid  = threadIdx.x;
    const int lane = tid & 63;
    const int g    = tid >> 6;
    const int l15  = lane & 15, quad = lane >> 4;
    const int bx   = blockIdx.x;
    const int d    = bx >> 6;
    const int jc   = (bx >> 1) & 31;
    const int mh   = bx & 1;
    const int m0   = mh * 64;
    const int grp  = (d * 2 + mh) * 64;   // 256 B apart: no false sharing

    // ---- stage W_hh slice into LDS (once per dispatch) ----
    {
        const unsigned short* wbase = whh + (size_t)d * GG * HH;
        #pragma unroll
        for (int it = 0; it < 16; it++){
            int idx  = it * 256 + tid;   // [0, 4096)
            int row  = idx >> 6;         // 0..63 = g*16 + j
            int col8 = idx & 63;
            int gg2 = row >> 4, jj2 = row & 15;
            short8 v = *(const short8*)(wbase + (size_t)(gg2 * 512 + jc * 16 + jj2) * HH + col8 * 8);
            *(short8*)&w_s[gg2][jj2][col8 * 8] = v;
        }
    }
    if (cw != nullptr && tid < NC * 16){
        int c = tid >> 4, j = tid & 15;
        cw_s[c][j] = cw[(size_t)c * 1024 + d * 512 + jc * 16 + j];
    }
    __syncthreads();

    const size_t hdoff = (size_t)d * BB * HH;

    for (int ls = 0; ls < nsteps; ls++){
        const int tt   = t0 + ls;
        const int time = d ? (TT - 1 - tt) : tt;
        const int slot = time & (CH - 1);
        const unsigned short* src = ((tt & 1) ? hB : hA) + hdoff;
        unsigned short*       dst = ((tt & 1) ? hA : hB) + hdoff;

        // ---- this gate's z = h_prev @ W_g^T (64 rows x 16 cols), B-frags from LDS ----
        f32x4 acc[4];
        #pragma unroll
        for (int mt = 0; mt < 4; mt++){ acc[mt][0]=0.f; acc[mt][1]=0.f; acc[mt][2]=0.f; acc[mt][3]=0.f; }

        const unsigned short* ap = src + (size_t)(m0 + l15) * HH + quad * 8;
        #pragma unroll
        for (int kk = 0; kk < 16; kk++){
            short8 bfr = *(const short8*)&w_s[g][l15][kk * 32 + quad * 8];
            short8 a0 = *(const short8*)(ap + 0 * 16 * HH + kk * 32);
            short8 a1 = *(const short8*)(ap + 1 * 16 * HH + kk * 32);
            short8 a2 = *(const short8*)(ap + 2 * 16 * HH + kk * 32);
            short8 a3 = *(const short8*)(ap + 3 * 16 * HH + kk * 32);
            acc[0] = __builtin_amdgcn_mfma_f32_16x16x32_bf16(a0, bfr, acc[0], 0, 0, 0);
            acc[1] = __builtin_amdgcn_mfma_f32_16x16x32_bf16(a1, bfr, acc[1], 0, 0, 0);
            acc[2] = __builtin_amdgcn_mfma_f32_16x16x32_bf16(a2, bfr, acc[2], 0, 0, 0);
            acc[3] = __builtin_amdgcn_mfma_f32_16x16x32_bf16(a3, bfr, acc[3], 0, 0, 0);
        }

        #pragma unroll
        for (int mt = 0; mt < 4; mt++)
            #pragma unroll
            for (int r = 0; r < 4; r++)
                z[(g * 64 + mt * 16 + quad * 4 + r) * 17 + l15] = acc[mt][r];

        __syncthreads();

        // ---- gate fusion: 64m x 8 j-pairs = 512 pair-cells / 256 threads ----
        {
            const int jp   = (tid & 7) * 2;
            const int mloc = tid >> 3;   // 0..31
            #pragma unroll
            for (int i = 0; i < 2; i++){
                const int m  = mloc * 2 + i;   // 0..63
                const int gm = m0 + m;
                const size_t prow = ((size_t)(d * CH + slot) * BB + gm) * GG + jc * 16 + jp;
                const size_t cix  = ((size_t)d * BB + gm) * HH + jc * 16 + jp;
                float hf[2];
                #pragma unroll
                for (int jj = 0; jj < 2; jj++){
                    const int j = jp + jj;
                    const float zi = z[(0 * 64 + m) * 17 + j] + bf2f(preC[prow + 0 * 512 + jj]);
                    const float zf = z[(1 * 64 + m) * 17 + j] + bf2f(preC[prow + 1 * 512 + jj]);
                    const float zg = z[(2 * 64 + m) * 17 + j] + bf2f(preC[prow + 2 * 512 + jj]);
                    const float zo = z[(3 * 64 + m) * 17 + j] + bf2f(preC[prow + 3 * 512 + jj]);
                    const float cn = sigm(zf) * cstate[cix + jj] + sigm(zi) * tanh_f(zg);
                    cstate[cix + jj] = cn;
                    hf[jj] = sigm(zo) * tanh_f(cn);
                }
                const unsigned int packed = (unsigned int)f2bf(hf[0]) | ((unsigned int)f2bf(hf[1]) << 16);
                __hip_atomic_store((unsigned int*)(dst + (size_t)gm * HH + jc * 16 + jp),
                                   packed, __ATOMIC_RELAXED, __HIP_MEMORY_SCOPE_AGENT);
                if (cw != nullptr){
                    hrow[m * 17 + jp]     = hf[0];
                    hrow[m * 17 + jp + 1] = hf[1];
                } else {
                    *(unsigned int*)(hs_out + ((size_t)time * BB + gm) * (2 * HH) + d * HH + jc * 16 + jp) = packed;
                }
            }
        }

        __syncthreads();

        // ---- fused emission partials (layer 1): em[time,b,:] += h . cls_w_slice ----
        if (cw != nullptr && tid < 64){
            const int m = tid, gm = m0 + m;
            float hv[16];
            #pragma unroll
            for (int k = 0; k < 16; k++) hv[k] = hrow[m * 17 + k];
            float* emr = em + ((size_t)time * BB + gm) * NC;
            #pragma unroll
            for (int c = 0; c < NC; c++){
                float s = 0.f;
                #pragma unroll
                for (int k = 0; k < 16; k++) s += hv[k] * cw_s[c][k];
                atomicAdd(emr + c, s);
            }
        }

        // ---- per-(d,mh) group barrier: 32 arrivals ----
        if (tid == 0){
            __builtin_amdgcn_fence(__ATOMIC_RELEASE, "agent");
            __hip_atomic_fetch_add(bar + grp, 1u, __ATOMIC_RELAXED, __HIP_MEMORY_SCOPE_AGENT);
            const unsigned int tgt = 32u * (unsigned int)(ls + 1);
            while (__hip_atomic_load(bar + grp, __ATOMIC_RELAXED, __HIP_MEMORY_SCOPE_AGENT) < tgt)
                __builtin_amdgcn_s_sleep(1);
            __builtin_amdgcn_fence(__ATOMIC_ACQUIRE, "agent");
        }
        __syncthreads();
    }
}

// ---------------- em init: em[t,b,c] = cls_b[c] ----------------
__global__ void eminit(const float* __restrict__ cb, float* __restrict__ em){
    int i = blockIdx.x * blockDim.x + threadIdx.x;
    if (i < TB * NC) em[i] = cb[i % NC];
}

// ---------------- CRF per-sequence ----------------
__global__ __launch_bounds__(64) void crf_k(const int* __restrict__ y,
                                            const float* __restrict__ em,
                                            const float* __restrict__ cstart,
                                            const float* __restrict__ cend,
                                            const float* __restrict__ ctr,
                                            float* __restrict__ llh){
    int b = blockIdx.x;
    int lane = threadIdx.x;

    float sp = 0.f; int cnt = 0;
    for (int t = lane; t < TT; t += 64){
        int yt = y[b * TT + t];
        bool mk = (yt > -1);
        cnt += mk ? 1 : 0;
        if (t >= 1 && mk){
            int yp  = y[b * TT + t - 1];
            int tag  = yt > 0 ? yt : 0;
            int tagp = yp > 0 ? yp : 0;
            sp += ctr[tagp * NC + tag] + em[((size_t)t * BB + b) * NC + tag];
        }
    }
    #pragma unroll
    for (int off = 32; off > 0; off >>= 1){
        sp  += __shfl_xor(sp, off, 64);
        cnt += __shfl_xor(cnt, off, 64);
    }

    float trc[NC];
    #pragma unroll
    for (int cc2 = 0; cc2 < NC; cc2++) trc[cc2] = 0.f;
    if (lane < NC){
        #pragma unroll
        for (int cc2 = 0; cc2 < NC; cc2++) trc[cc2] = ctr[cc2 * NC + lane];
    }
    float alpha = -1e30f;
    if (lane < NC) alpha = cstart[lane] + em[(size_t)b * NC + lane];

    for (int t = 1; t < TT; t++){
        int yt = y[b * TT + t];
        bool mk = (yt > -1);
        float e = (lane < NC) ? em[((size_t)t * BB + b) * NC + lane] : 0.f;
        float v[NC]; float mx = -1e30f;
        #pragma unroll
        for (int cc2 = 0; cc2 < NC; cc2++){
            float ac = __shfl(alpha, cc2, 64);
            v[cc2] = ac + trc[cc2];
            mx = fmaxf(mx, v[cc2]);
        }
        float s = 0.f;
        #pragma unroll
        for (int cc2 = 0; cc2 < NC; cc2++) s += __expf(v[cc2] - mx);
        float nxt = mx + __logf(s) + e;
        if (mk && lane < NC) alpha = nxt;
    }

    float val = (lane < NC) ? (alpha + cend[lane]) : -1e30f;
    float mx = -1e30f;
    #pragma unroll
    for (int cc2 = 0; cc2 < NC; cc2++) mx = fmaxf(mx, __shfl(val, cc2, 64));
    float s = 0.f;
    #pragma unroll
    for (int cc2 = 0; cc2 < NC; cc2++) s += __expf(__shfl(val, cc2, 64) - mx);
    float denom = mx + __logf(s);

    if (lane == 0){
        int y0 = y[b * TT];
        int tag0 = y0 > 0 ? y0 : 0;
        int se = cnt - 1;
        if (se < 0) se = 0;
        int yl = y[b * TT + se];
        int tagl = yl > 0 ? yl : 0;
        float score = sp + cstart[tag0] + em[(size_t)b * NC + tag0] + cend[tagl];
        llh[b] = score - denom;
    }
}

__global__ void final_k(const float* __restrict__ llh, float* __restrict__ out){
    __shared__ float sm[128];
    int i = threadIdx.x;
    sm[i] = llh[i];
    __syncthreads();
    for (int s = 64; s > 0; s >>= 1){
        if (i < s) sm[i] += sm[i + s];
        __syncthreads();
    }
    if (i == 0) out[0] = -sm[0] / 128.f;
}

__global__ void sentinel_k(float* out, float v){ out[0] = v; }

extern "C" void kernel_launch(void* const* d_in, const int* in_sizes, int n_in,
                              void* d_out, int out_size, void* d_ws, size_t ws_size,
                              hipStream_t stream) {
    const int*   x     = (const int*)d_in[0];
    const int*   y     = (const int*)d_in[1];
    const float* embed = (const float*)d_in[2];
    const float* wih0  = (const float*)d_in[3];
    const float* whh0  = (const float*)d_in[4];
    const float* b0    = (const float*)d_in[5];
    const float* wih1  = (const float*)d_in[6];
    const float* whh1  = (const float*)d_in[7];
    const float* b1    = (const float*)d_in[8];
    const float* clsw  = (const float*)d_in[9];
    const float* clsb  = (const float*)d_in[10];
    const float* cst   = (const float*)d_in[11];
    const float* cen   = (const float*)d_in[12];
    const float* ctr   = (const float*)d_in[13];
    float* out = (float*)d_out;

    const size_t sz_w0   = (size_t)2 * GG * HH * 2;     // 4.19 MB each
    const size_t sz_w1   = (size_t)2 * GG * 1024 * 2;   // 8.39 MB
    const size_t sz_xs   = (size_t)TB * HH * 2;         // 33.55 MB
    const size_t sz_hs0  = (size_t)TB * 1024 * 2;       // 67.1 MB
    const size_t sz_h    = (size_t)2 * BB * HH * 2;
    const size_t sz_c    = (size_t)2 * BB * HH * 4;
    const size_t sz_emis = (size_t)TB * NC * 4;
    const size_t sz_llh  = (size_t)BB * 4;
    const size_t sz_bar  = 1024;
    auto rup = [](size_t v){ return (v + 255) & ~(size_t)255; };
    size_t fixed = rup(sz_w0) * 3 + rup(sz_w1) + rup(sz_xs) + rup(sz_hs0)
                 + rup(sz_h) * 2 + rup(sz_c) + rup(sz_emis) + rup(sz_llh) + rup(sz_bar);

    // largest power-of-2 chunk (timesteps of pre per direction) that fits
    const int cands[7] = {256, 128, 64, 32, 16, 8, 4};
    int CH = 0;
    for (int i = 0; i < 7; i++){
        size_t need = fixed + rup((size_t)2 * cands[i] * BB * GG * 2);
        if (need <= ws_size){ CH = cands[i]; break; }
    }
    if (CH == 0){
        sentinel_k<<<1, 1, 0, stream>>>(out, -(float)(ws_size >> 20));
        return;
    }

    char* ws = (char*)d_ws;
    size_t off = 0;
    auto alloc = [&](size_t bytes) -> void* {
        void* p = (void*)(ws + off);
        off += (bytes + 255) & ~(size_t)255;
        return p;
    };
    unsigned short* wih0b = (unsigned short*)alloc(sz_w0);
    unsigned short* whh0b = (unsigned short*)alloc(sz_w0);
    unsigned short* whh1b = (unsigned short*)alloc(sz_w0);
    unsigned short* wih1b = (unsigned short*)alloc(sz_w1);
    unsigned short* xs    = (unsigned short*)alloc(sz_xs);
    unsigned short* hs0   = (unsigned short*)alloc(sz_hs0);
    unsigned short* hA    = (unsigned short*)alloc(sz_h);
    unsigned short* hB    = (unsigned short*)alloc(sz_h);
    float*          cbuf  = (float*)alloc(sz_c);
    float*          emis  = (float*)alloc(sz_emis);
    float*          llh   = (float*)alloc(sz_llh);
    unsigned int*   bar   = (unsigned int*)alloc(sz_bar);
    unsigned short* preC  = (unsigned short*)alloc((size_t)2 * CH * BB * GG * 2);

    castbf<<<(2 * GG * HH + 255) / 256, 256, 0, stream>>>(wih0, wih0b, 2 * GG * HH);
    castbf<<<(2 * GG * HH + 255) / 256, 256, 0, stream>>>(whh0, whh0b, 2 * GG * HH);
    castbf<<<(2 * GG * 1024 + 255) / 256, 256, 0, stream>>>(wih1, wih1b, 2 * GG * 1024);
    castbf<<<(2 * GG * HH + 255) / 256, 256, 0, stream>>>(whh1, whh1b, 2 * GG * HH);

    embed_k<<<TB / 4, 256, 0, stream>>>(x, embed, xs);

    const int nch = TT / CH;

    // ---------- layer 0 (writes hs0) ----------
    (void)hipMemsetAsync(hA, 0, sz_h, stream);
    (void)hipMemsetAsync(cbuf, 0, sz_c, stream);
    for (int c = 0; c < nch; c++){
        int t0f = c * CH;
        int t0b = TT - (c + 1) * CH;
        gemm2<<<dim3(CH, GG / 128, 2), 256, 0, stream>>>(
            xs + (size_t)t0f * BB * HH, xs + (size_t)t0b * BB * HH,
            wih0b, b0, preC, HH, CH);
        (void)hipMemsetAsync(bar, 0, sz_bar, stream);
        lstm_seq<<<128, 256, 0, stream>>>(preC, whh0b, hA, hB, cbuf, hs0,
                                          nullptr, emis, c * CH, CH, CH, bar);
    }

    // ---------- emissions init ----------
    eminit<<<(TB * NC + 255) / 256, 256, 0, stream>>>(clsb, emis);

    // ---------- layer 1 (fused emissions, no hs1) ----------
    (void)hipMemsetAsync(hA, 0, sz_h, stream);
    (void)hipMemsetAsync(cbuf, 0, sz_c, stream);
    for (int c = 0; c < nch; c++){
        int t0f = c * CH;
        int t0b = TT - (c + 1) * CH;
        gemm2<<<dim3(CH, GG / 128, 2), 256, 0, stream>>>(
            hs0 + (size_t)t0f * BB * 1024, hs0 + (size_t)t0b * BB * 1024,
            wih1b, b1, preC, 1024, CH);
        (void)hipMemsetAsync(bar, 0, sz_bar, stream);
        lstm_seq<<<128, 256, 0, stream>>>(preC, whh1b, hA, hB, cbuf, hs0,
                                          clsw, emis, c * CH, CH, CH, bar);
    }

    crf_k<<<BB, 64, 0, stream>>>(y, emis, cst, cen, ctr, llh);
    final_k<<<1, 128, 0, stream>>>(llh, out);
}

// Round 6
// 9331.112 us; speedup vs baseline: 1.1805x; 1.1805x over previous
//
#include <hip/hip_runtime.h>
#include <hip/hip_bf16.h>

#define VV 30000
#define HH 512
#define NC 9
#define BB 128
#define TT 256
#define GG 2048
#define TB (TT*BB)

using short8 = __attribute__((ext_vector_type(8))) short;
using f32x4  = __attribute__((ext_vector_type(4))) float;

__device__ inline float bf2f(unsigned short u){
    union { unsigned int i; float f; } v; v.i = ((unsigned int)u) << 16; return v.f;
}
__device__ inline unsigned short f2bf(float f){
    union { unsigned int i; float f; } v; v.f = f;
    unsigned int x = v.i;
    unsigned int r = (x + 0x7fffu + ((x >> 16) & 1u)) >> 16;
    return (unsigned short)r;
}
__device__ inline float sigm(float x){
    if (x >= 0.f){ return 1.f / (1.f + __expf(-x)); }
    float e = __expf(x); return e / (1.f + e);
}
__device__ inline float tanh_f(float x){
    float ax = fabsf(x);
    float e = __expf(-2.f * ax);
    float t = (1.f - e) / (1.f + e);
    return copysignf(t, x);
}

// ---------------- weight cast fp32 -> bf16 ----------------
__global__ void castbf(const float* __restrict__ in, unsigned short* __restrict__ out, int n){
    int i = blockIdx.x * blockDim.x + threadIdx.x;
    if (i < n) out[i] = f2bf(in[i]);
}

// ---------------- embedding + renorm -> xs bf16 [T*B][H] ----------------
__global__ __launch_bounds__(256) void embed_k(const int* __restrict__ x,
                                               const float* __restrict__ embed,
                                               unsigned short* __restrict__ xs){
    int wid  = (int)((blockIdx.x * blockDim.x + threadIdx.x) >> 6);
    int lane = threadIdx.x & 63;
    if (wid >= TB) return;
    int t = wid >> 7, b = wid & 127;
    int tok = x[b * TT + t];
    const float4* e = (const float4*)(embed + (size_t)tok * HH);
    float4 v0 = e[lane], v1 = e[lane + 64];
    float ss = v0.x*v0.x + v0.y*v0.y + v0.z*v0.z + v0.w*v0.w
             + v1.x*v1.x + v1.y*v1.y + v1.z*v1.z + v1.w*v1.w;
    #pragma unroll
    for (int off = 32; off > 0; off >>= 1) ss += __shfl_xor(ss, off, 64);
    float nrm = sqrtf(ss);
    float sc = (nrm > 1.f) ? 1.f / (nrm + 1e-7f) : 1.f;
    unsigned short* dst = xs + (size_t)wid * HH;
    ushort4 o0, o1;
    o0.x = f2bf(v0.x * sc); o0.y = f2bf(v0.y * sc); o0.z = f2bf(v0.z * sc); o0.w = f2bf(v0.w * sc);
    o1.x = f2bf(v1.x * sc); o1.y = f2bf(v1.y * sc); o1.z = f2bf(v1.z * sc); o1.w = f2bf(v1.w * sc);
    ((ushort4*)dst)[lane]      = o0;
    ((ushort4*)dst)[lane + 64] = o1;
}

// ---------------- bf16 GEMM (both dirs via blockIdx.z): C = A@W^T + bias ----------------
__global__ __launch_bounds__(256) void gemm2(const unsigned short* __restrict__ A0,
                                             const unsigned short* __restrict__ A1,
                                             const unsigned short* __restrict__ Wb_,
                                             const float* __restrict__ bias,
                                             unsigned short* __restrict__ Cout,
                                             int K, int CH){
    const int dz = blockIdx.z;
    const unsigned short* A  = dz ? A1 : A0;
    const unsigned short* W  = Wb_ + (size_t)dz * GG * K;
    const float*          bd = bias + dz * GG;
    unsigned short*       C  = Cout + (size_t)dz * CH * BB * GG;

    int lane = threadIdx.x & 63;
    int wv   = threadIdx.x >> 6;
    int m0   = blockIdx.x * 128 + (wv >> 1) * 64;
    int n0   = blockIdx.y * 128 + (wv & 1) * 64;
    int l15  = lane & 15, quad = lane >> 4;

    f32x4 acc[4][4];
    #pragma unroll
    for (int i = 0; i < 4; i++)
        #pragma unroll
        for (int j = 0; j < 4; j++){ acc[i][j][0]=0.f; acc[i][j][1]=0.f; acc[i][j][2]=0.f; acc[i][j][3]=0.f; }

    const unsigned short* Ab = A + (size_t)(m0 + l15) * K + quad * 8;
    const unsigned short* Wp = W + (size_t)(n0 + l15) * K + quad * 8;

    for (int kk = 0; kk < K; kk += 32){
        short8 a[4], bfr[4];
        #pragma unroll
        for (int i = 0; i < 4; i++) a[i]   = *(const short8*)(Ab + (size_t)i * 16 * K + kk);
        #pragma unroll
        for (int j = 0; j < 4; j++) bfr[j] = *(const short8*)(Wp + (size_t)j * 16 * K + kk);
        #pragma unroll
        for (int i = 0; i < 4; i++)
            #pragma unroll
            for (int j = 0; j < 4; j++)
                acc[i][j] = __builtin_amdgcn_mfma_f32_16x16x32_bf16(a[i], bfr[j], acc[i][j], 0, 0, 0);
    }

    #pragma unroll
    for (int i = 0; i < 4; i++){
        #pragma unroll
        for (int j = 0; j < 4; j++){
            int n = n0 + j * 16 + l15;
            float bn = bd[n];
            #pragma unroll
            for (int r = 0; r < 4; r++){
                int m = m0 + i * 16 + quad * 4 + r;
                C[(size_t)m * GG + n] = f2bf(acc[i][j][r] + bn);
            }
        }
    }
}

// ---------------- persistent BiLSTM recurrence (fence-free) ----------------
// grid: 128 blocks = d(2) x jc(32) x mh(2); block 256 = 4 waves (one 16-row
// m-subtile each, computing ALL 4 gates -> epilogue is register-resident).
// W_hh slice in LDS (staged once). h crosses blocks ONLY via agent-scope
// relaxed atomic load/store (coherence-point access; no fences -> L1/L2 stay
// warm for W/preC/cstate across all steps). Barrier = per-(d,mh) flag vector:
// one store + parallel 32-flag poll by wave 0.
__global__ __launch_bounds__(256) void lstm_seq(const unsigned short* __restrict__ preC, // [2][CH][128][2048]
                                                const unsigned short* __restrict__ whh,  // [2][2048][512]
                                                unsigned short* __restrict__ hA,         // [2][128][512]
                                                unsigned short* __restrict__ hB,
                                                float* __restrict__ cstate,              // [2][128][512]
                                                unsigned short* __restrict__ hs_out,     // [TB][1024] (layer0)
                                                const float* __restrict__ cw,            // [9][1024] (layer1) or null
                                                float* __restrict__ em,                  // [T*B][9]  (layer1)
                                                int t0, int nsteps, int CH,
                                                unsigned int* __restrict__ bar){
    __shared__ unsigned short w_s[4][16][520];  // 66.6 KB, +8 pad -> 2-way conflicts (free)
    __shared__ float hrow[64 * 17];             // 4.3 KB (layer-1 emission staging)
    __shared__ float cw_s[NC][16];

    const int tid  = threadIdx.x;
    const int lane = tid & 63;
    const int wv   = tid >> 6;
    const int l15  = lane & 15, quad = lane >> 4;
    const int bx   = blockIdx.x;
    const int d    = bx >> 6;
    const int jc   = (bx >> 1) & 31;
    const int mh   = bx & 1;
    const int m0   = mh * 64;
    const int grp  = d * 2 + mh;

    // ---- stage W_hh slice into LDS (once per dispatch) ----
    {
        const unsigned short* wbase = whh + (size_t)d * GG * HH;
        #pragma unroll
        for (int it = 0; it < 16; it++){
            int idx  = it * 256 + tid;   // [0, 4096) short8-chunks
            int row  = idx >> 6;         // 0..63 = g*16 + j
            int col8 = idx & 63;
            int g2 = row >> 4, j2 = row & 15;
            short8 v = *(const short8*)(wbase + (size_t)(g2 * 512 + jc * 16 + j2) * HH + col8 * 8);
            *(short8*)&w_s[g2][j2][col8 * 8] = v;
        }
    }
    if (cw != nullptr && tid < NC * 16){
        int c = tid >> 4, j = tid & 15;
        cw_s[c][j] = cw[(size_t)c * 1024 + d * 512 + jc * 16 + j];
    }
    __syncthreads();

    const size_t hdoff = (size_t)d * BB * HH;
    const int myrow = m0 + wv * 16 + l15;   // A-frag row for this lane
    const int j = jc * 16 + l15;            // hidden col for epilogue

    for (int ls = 0; ls < nsteps; ls++){
        const int tt   = t0 + ls;
        const int time = d ? (TT - 1 - tt) : tt;
        const int slot = time & (CH - 1);
        const unsigned short* srcB = ((tt & 1) ? hB : hA) + hdoff;
        unsigned short*       dstB = ((tt & 1) ? hA : hB) + hdoff;

        // ---- coherent A-loads: this wave's 16 h-rows (64 sc-dwords/lane) ----
        const unsigned int* hsrc = (const unsigned int*)(srcB + (size_t)myrow * HH);
        unsigned int areg[16][4];
        #pragma unroll
        for (int kk = 0; kk < 16; kk++){
            #pragma unroll
            for (int q = 0; q < 4; q++)
                areg[kk][q] = __hip_atomic_load(hsrc + kk * 16 + quad * 4 + q,
                                                __ATOMIC_RELAXED, __HIP_MEMORY_SCOPE_AGENT);
        }

        // ---- all 4 gates for this m-subtile ----
        f32x4 acc[4];
        #pragma unroll
        for (int g = 0; g < 4; g++){ acc[g][0]=0.f; acc[g][1]=0.f; acc[g][2]=0.f; acc[g][3]=0.f; }
        #pragma unroll
        for (int kk = 0; kk < 16; kk++){
            union { unsigned int u[4]; short8 s; } au;
            au.u[0] = areg[kk][0]; au.u[1] = areg[kk][1];
            au.u[2] = areg[kk][2]; au.u[3] = areg[kk][3];
            #pragma unroll
            for (int g = 0; g < 4; g++){
                short8 b = *(const short8*)&w_s[g][l15][kk * 32 + quad * 8];
                acc[g] = __builtin_amdgcn_mfma_f32_16x16x32_bf16(au.s, b, acc[g], 0, 0, 0);
            }
        }

        // ---- register-resident gate fusion (C-layout: lane has all 4 gates) ----
        #pragma unroll
        for (int r = 0; r < 4; r++){
            const int gm = m0 + wv * 16 + quad * 4 + r;
            const size_t prow = ((size_t)(d * CH + slot) * BB + gm) * GG + j;
            const float zi = acc[0][r] + bf2f(preC[prow]);
            const float zf = acc[1][r] + bf2f(preC[prow + 512]);
            const float zg = acc[2][r] + bf2f(preC[prow + 1024]);
            const float zo = acc[3][r] + bf2f(preC[prow + 1536]);
            const size_t cix = ((size_t)d * BB + gm) * HH + j;
            const float cn = sigm(zf) * cstate[cix] + sigm(zi) * tanh_f(zg);
            cstate[cix] = cn;
            const float hf = sigm(zo) * tanh_f(cn);
            __hip_atomic_store(dstB + (size_t)gm * HH + j, f2bf(hf),
                               __ATOMIC_RELAXED, __HIP_MEMORY_SCOPE_AGENT);
            if (cw != nullptr) hrow[(wv * 16 + quad * 4 + r) * 17 + l15] = hf;
            else hs_out[((size_t)time * BB + gm) * (2 * HH) + d * HH + j] = f2bf(hf);
        }

        // ---- fused emission partials (layer 1) ----
        if (cw != nullptr){
            __syncthreads();
            if (tid < 64){
                const int m = tid, gm = m0 + m;
                float* emr = em + ((size_t)time * BB + gm) * NC;
                #pragma unroll
                for (int c = 0; c < NC; c++){
                    float s = 0.f;
                    #pragma unroll
                    for (int k = 0; k < 16; k++) s += hrow[m * 17 + k] * cw_s[c][k];
                    atomicAdd(emr + c, s);
                }
            }
        }

        // ---- barrier: syncthreads drains every thread's stores (vmcnt 0) ----
        __syncthreads();
        if (tid == 0)
            __hip_atomic_store(&bar[grp * 32 + jc], (unsigned int)(ls + 1),
                               __ATOMIC_RELAXED, __HIP_MEMORY_SCOPE_AGENT);
        if (ls + 1 < nsteps){
            if (tid < 64){
                const unsigned int tgt = (unsigned int)(ls + 1);
                const unsigned int* fl = bar + grp * 32 + (tid & 31);
                while (__hip_atomic_load(fl, __ATOMIC_RELAXED, __HIP_MEMORY_SCOPE_AGENT) < tgt)
                    __builtin_amdgcn_s_sleep(2);
            }
            __syncthreads();
            __builtin_amdgcn_fence(__ATOMIC_ACQUIRE, "workgroup"); // ordering only; no cache inv
        }
    }
}

// ---------------- em init: em[t,b,c] = cls_b[c] ----------------
__global__ void eminit(const float* __restrict__ cb, float* __restrict__ em){
    int i = blockIdx.x * blockDim.x + threadIdx.x;
    if (i < TB * NC) em[i] = cb[i % NC];
}

// ---------------- CRF per-sequence ----------------
__global__ __launch_bounds__(64) void crf_k(const int* __restrict__ y,
                                            const float* __restrict__ em,
                                            const float* __restrict__ cstart,
                                            const float* __restrict__ cend,
                                            const float* __restrict__ ctr,
                                            float* __restrict__ llh){
    int b = blockIdx.x;
    int lane = threadIdx.x;

    float sp = 0.f; int cnt = 0;
    for (int t = lane; t < TT; t += 64){
        int yt = y[b * TT + t];
        bool mk = (yt > -1);
        cnt += mk ? 1 : 0;
        if (t >= 1 && mk){
            int yp  = y[b * TT + t - 1];
            int tag  = yt > 0 ? yt : 0;
            int tagp = yp > 0 ? yp : 0;
            sp += ctr[tagp * NC + tag] + em[((size_t)t * BB + b) * NC + tag];
        }
    }
    #pragma unroll
    for (int off = 32; off > 0; off >>= 1){
        sp  += __shfl_xor(sp, off, 64);
        cnt += __shfl_xor(cnt, off, 64);
    }

    float trc[NC];
    #pragma unroll
    for (int cc2 = 0; cc2 < NC; cc2++) trc[cc2] = 0.f;
    if (lane < NC){
        #pragma unroll
        for (int cc2 = 0; cc2 < NC; cc2++) trc[cc2] = ctr[cc2 * NC + lane];
    }
    float alpha = -1e30f;
    if (lane < NC) alpha = cstart[lane] + em[(size_t)b * NC + lane];

    for (int t = 1; t < TT; t++){
        int yt = y[b * TT + t];
        bool mk = (yt > -1);
        float e = (lane < NC) ? em[((size_t)t * BB + b) * NC + lane] : 0.f;
        float v[NC]; float mx = -1e30f;
        #pragma unroll
        for (int cc2 = 0; cc2 < NC; cc2++){
            float ac = __shfl(alpha, cc2, 64);
            v[cc2] = ac + trc[cc2];
            mx = fmaxf(mx, v[cc2]);
        }
        float s = 0.f;
        #pragma unroll
        for (int cc2 = 0; cc2 < NC; cc2++) s += __expf(v[cc2] - mx);
        float nxt = mx + __logf(s) + e;
        if (mk && lane < NC) alpha = nxt;
    }

    float val = (lane < NC) ? (alpha + cend[lane]) : -1e30f;
    float mx = -1e30f;
    #pragma unroll
    for (int cc2 = 0; cc2 < NC; cc2++) mx = fmaxf(mx, __shfl(val, cc2, 64));
    float s = 0.f;
    #pragma unroll
    for (int cc2 = 0; cc2 < NC; cc2++) s += __expf(__shfl(val, cc2, 64) - mx);
    float denom = mx + __logf(s);

    if (lane == 0){
        int y0 = y[b * TT];
        int tag0 = y0 > 0 ? y0 : 0;
        int se = cnt - 1;
        if (se < 0) se = 0;
        int yl = y[b * TT + se];
        int tagl = yl > 0 ? yl : 0;
        float score = sp + cstart[tag0] + em[(size_t)b * NC + tag0] + cend[tagl];
        llh[b] = score - denom;
    }
}

__global__ void final_k(const float* __restrict__ llh, float* __restrict__ out){
    __shared__ float sm[128];
    int i = threadIdx.x;
    sm[i] = llh[i];
    __syncthreads();
    for (int s = 64; s > 0; s >>= 1){
        if (i < s) sm[i] += sm[i + s];
        __syncthreads();
    }
    if (i == 0) out[0] = -sm[0] / 128.f;
}

__global__ void sentinel_k(float* out, float v){ out[0] = v; }

extern "C" void kernel_launch(void* const* d_in, const int* in_sizes, int n_in,
                              void* d_out, int out_size, void* d_ws, size_t ws_size,
                              hipStream_t stream) {
    const int*   x     = (const int*)d_in[0];
    const int*   y     = (const int*)d_in[1];
    const float* embed = (const float*)d_in[2];
    const float* wih0  = (const float*)d_in[3];
    const float* whh0  = (const float*)d_in[4];
    const float* b0    = (const float*)d_in[5];
    const float* wih1  = (const float*)d_in[6];
    const float* whh1  = (const float*)d_in[7];
    const float* b1    = (const float*)d_in[8];
    const float* clsw  = (const float*)d_in[9];
    const float* clsb  = (const float*)d_in[10];
    const float* cst   = (const float*)d_in[11];
    const float* cen   = (const float*)d_in[12];
    const float* ctr   = (const float*)d_in[13];
    float* out = (float*)d_out;

    const size_t sz_w0   = (size_t)2 * GG * HH * 2;
    const size_t sz_w1   = (size_t)2 * GG * 1024 * 2;
    const size_t sz_xs   = (size_t)TB * HH * 2;
    const size_t sz_hs0  = (size_t)TB * 1024 * 2;
    const size_t sz_h    = (size_t)2 * BB * HH * 2;
    const size_t sz_c    = (size_t)2 * BB * HH * 4;
    const size_t sz_emis = (size_t)TB * NC * 4;
    const size_t sz_llh  = (size_t)BB * 4;
    const size_t sz_bar  = 1024;
    auto rup = [](size_t v){ return (v + 255) & ~(size_t)255; };
    size_t fixed = rup(sz_w0) * 3 + rup(sz_w1) + rup(sz_xs) + rup(sz_hs0)
                 + rup(sz_h) * 2 + rup(sz_c) + rup(sz_emis) + rup(sz_llh) + rup(sz_bar);

    const int cands[7] = {256, 128, 64, 32, 16, 8, 4};
    int CH = 0;
    for (int i = 0; i < 7; i++){
        size_t need = fixed + rup((size_t)2 * cands[i] * BB * GG * 2);
        if (need <= ws_size){ CH = cands[i]; break; }
    }
    if (CH == 0){
        sentinel_k<<<1, 1, 0, stream>>>(out, -(float)(ws_size >> 20));
        return;
    }

    char* ws = (char*)d_ws;
    size_t off = 0;
    auto alloc = [&](size_t bytes) -> void* {
        void* p = (void*)(ws + off);
        off += (bytes + 255) & ~(size_t)255;
        return p;
    };
    unsigned short* wih0b = (unsigned short*)alloc(sz_w0);
    unsigned short* whh0b = (unsigned short*)alloc(sz_w0);
    unsigned short* whh1b = (unsigned short*)alloc(sz_w0);
    unsigned short* wih1b = (unsigned short*)alloc(sz_w1);
    unsigned short* xs    = (unsigned short*)alloc(sz_xs);
    unsigned short* hs0   = (unsigned short*)alloc(sz_hs0);
    unsigned short* hA    = (unsigned short*)alloc(sz_h);
    unsigned short* hB    = (unsigned short*)alloc(sz_h);
    float*          cbuf  = (float*)alloc(sz_c);
    float*          emis  = (float*)alloc(sz_emis);
    float*          llh   = (float*)alloc(sz_llh);
    unsigned int*   bar   = (unsigned int*)alloc(sz_bar);
    unsigned short* preC  = (unsigned short*)alloc((size_t)2 * CH * BB * GG * 2);

    castbf<<<(2 * GG * HH + 255) / 256, 256, 0, stream>>>(wih0, wih0b, 2 * GG * HH);
    castbf<<<(2 * GG * HH + 255) / 256, 256, 0, stream>>>(whh0, whh0b, 2 * GG * HH);
    castbf<<<(2 * GG * 1024 + 255) / 256, 256, 0, stream>>>(wih1, wih1b, 2 * GG * 1024);
    castbf<<<(2 * GG * HH + 255) / 256, 256, 0, stream>>>(whh1, whh1b, 2 * GG * HH);

    embed_k<<<TB / 4, 256, 0, stream>>>(x, embed, xs);

    const int nch = TT / CH;

    // ---------- layer 0 (writes hs0) ----------
    (void)hipMemsetAsync(hA, 0, sz_h, stream);
    (void)hipMemsetAsync(cbuf, 0, sz_c, stream);
    for (int c = 0; c < nch; c++){
        int t0f = c * CH;
        int t0b = TT - (c + 1) * CH;
        gemm2<<<dim3(CH, GG / 128, 2), 256, 0, stream>>>(
            xs + (size_t)t0f * BB * HH, xs + (size_t)t0b * BB * HH,
            wih0b, b0, preC, HH, CH);
        (void)hipMemsetAsync(bar, 0, sz_bar, stream);
        lstm_seq<<<128, 256, 0, stream>>>(preC, whh0b, hA, hB, cbuf, hs0,
                                          nullptr, emis, c * CH, CH, CH, bar);
    }

    // ---------- emissions init ----------
    eminit<<<(TB * NC + 255) / 256, 256, 0, stream>>>(clsb, emis);

    // ---------- layer 1 (fused emissions, no hs1) ----------
    (void)hipMemsetAsync(hA, 0, sz_h, stream);
    (void)hipMemsetAsync(cbuf, 0, sz_c, stream);
    for (int c = 0; c < nch; c++){
        int t0f = c * CH;
        int t0b = TT - (c + 1) * CH;
        gemm2<<<dim3(CH, GG / 128, 2), 256, 0, stream>>>(
            hs0 + (size_t)t0f * BB * 1024, hs0 + (size_t)t0b * BB * 1024,
            wih1b, b1, preC, 1024, CH);
        (void)hipMemsetAsync(bar, 0, sz_bar, stream);
        lstm_seq<<<128, 256, 0, stream>>>(preC, whh1b, hA, hB, cbuf, hs0,
                                          clsw, emis, c * CH, CH, CH, bar);
    }

    crf_k<<<BB, 64, 0, stream>>>(y, emis, cst, cen, ctr, llh);
    final_k<<<1, 128, 0, stream>>>(llh, out);
}